// Round 2
// baseline (27571.796 us; speedup 1.0000x reference)
//
#include <hip/hip_runtime.h>
#include <hip/hip_bf16.h>

#define TPB 256
typedef __hip_bfloat16 bf16;
typedef __hip_bfloat162 bf162;

__device__ __forceinline__ float sigmoidf_(float v){ return 1.0f/(1.0f+expf(-v)); }

// ---- weight transpose: [3,3,CI,CO] -> [9,CO,CI] (ci contiguous per output channel)
__global__ void kTransposeW(const float* __restrict__ w, float* __restrict__ wT, int CI, int CO){
    int idx = blockIdx.x*TPB + threadIdx.x;
    int total = 9*CI*CO;
    if (idx >= total) return;
    int ci = idx % CI;
    int co = (idx / CI) % CO;
    int kk = idx / (CI*CO);
    wT[idx] = w[(kk*CI + ci)*CO + co];
}

// ---- conv1: x[32,256,256,1] f32 -> h1[32,128,128,32] bf16, stride 2 SAME(pad lo=0), relu
__global__ void kConv1(const float* __restrict__ x, const float* __restrict__ w,
                       const float* __restrict__ b, bf16* __restrict__ y){
    int idx = blockIdx.x*TPB + threadIdx.x;   // 16777216
    int co = idx & 31;
    int ow = (idx >> 5) & 127;
    int oh = (idx >> 12) & 127;
    int n  = idx >> 19;
    float acc = b[co];
    #pragma unroll
    for (int kh = 0; kh < 3; ++kh){
        int ih = oh*2 + kh; if (ih >= 256) break;
        #pragma unroll
        for (int kw = 0; kw < 3; ++kw){
            int iw = ow*2 + kw; if (iw >= 256) break;
            acc = fmaf(x[(n*256 + ih)*256 + iw], w[(kh*3 + kw)*32 + co], acc);
        }
    }
    y[idx] = __float2bfloat16(fmaxf(acc, 0.f));
}

// ---- generic stride-2 SAME conv (pad lo=0), relu; x bf16, wT f32 [9,CO,CI], y bf16
template<int CI, int CO>
__global__ void kConvS2(const bf16* __restrict__ x, const float* __restrict__ wT,
                        const float* __restrict__ b, bf16* __restrict__ y,
                        int H, int W, int OH, int OW, int total){
    int idx = blockIdx.x*TPB + threadIdx.x;
    if (idx >= total) return;
    int co = idx % CO;
    int t  = idx / CO;
    int ow = t % OW; t /= OW;
    int oh = t % OH;
    int n  = t / OH;
    float acc = b[co];
    for (int kh = 0; kh < 3; ++kh){
        int ih = oh*2 + kh; if (ih >= H) break;
        for (int kw = 0; kw < 3; ++kw){
            int iw = ow*2 + kw; if (iw >= W) break;
            const bf162* x2 = reinterpret_cast<const bf162*>(x + ((size_t)(n*H + ih)*W + iw)*CI);
            const float2* w2 = reinterpret_cast<const float2*>(wT + ((kh*3 + kw)*CO + co)*CI);
            #pragma unroll
            for (int c = 0; c < CI/2; ++c){
                float2 xv = __bfloat1622float2(x2[c]);
                float2 wv = w2[c];
                acc = fmaf(xv.x, wv.x, acc);
                acc = fmaf(xv.y, wv.y, acc);
            }
        }
    }
    y[idx] = __float2bfloat16(fmaxf(acc, 0.f));
}

__global__ void kZero(float* __restrict__ p, int n){
    int i = blockIdx.x*TPB + threadIdx.x;
    if (i < n) p[i] = 0.f;
}

// ---- encoder dense: z[32,100] += h3[32,131072](bf16) @ wd[131072,100]
#define KB 256
__global__ void kDenseEnc(const bf16* __restrict__ h, const float* __restrict__ wd,
                          float* __restrict__ z){
    __shared__ float hs[32][KB];     // 32 KB
    int k0 = blockIdx.x * KB;
    for (int i = threadIdx.x; i < 32*KB; i += TPB){
        int bb = i >> 8;
        int kk = i & (KB-1);
        hs[bb][kk] = __bfloat162float(h[bb*131072 + k0 + kk]);
    }
    __syncthreads();
    int j = threadIdx.x;
    if (j < 100){
        float acc[32];
        #pragma unroll
        for (int bb = 0; bb < 32; ++bb) acc[bb] = 0.f;
        for (int kk = 0; kk < KB; ++kk){
            float wv = wd[(size_t)(k0 + kk)*100 + j];
            #pragma unroll
            for (int bb = 0; bb < 32; ++bb) acc[bb] = fmaf(hs[bb][kk], wv, acc[bb]);
        }
        #pragma unroll
        for (int bb = 0; bb < 32; ++bb) atomicAdd(&z[bb*100 + j], acc[bb]);
    }
}

// ---- VQ: q[b] = emb[argmin_k ||z[b]+bd - emb[k]||^2], first-min-wins
__global__ void kVQ(const float* __restrict__ z, const float* __restrict__ bd,
                    const float* __restrict__ emb, float* __restrict__ q){
    __shared__ float zb[100];
    __shared__ float d2s[128];
    __shared__ int best;
    int b = blockIdx.x;
    int t = threadIdx.x;           // 128
    if (t < 100) zb[t] = z[b*100 + t] + bd[t];
    __syncthreads();
    if (t < 100){
        float acc = 0.f;
        for (int d = 0; d < 100; ++d){
            float df = zb[d] - emb[t*100 + d];
            acc = fmaf(df, df, acc);
        }
        d2s[t] = acc;
    }
    __syncthreads();
    if (t == 0){
        float m = d2s[0]; int mi = 0;
        for (int k = 1; k < 100; ++k){ if (d2s[k] < m){ m = d2s[k]; mi = k; } }
        best = mi;
    }
    __syncthreads();
    if (t < 100) q[b*100 + t] = emb[best*100 + t];
}

// ---- decoder dense: d0[32,32768] = relu(q @ we + be), bf16 out
__global__ void kDenseDec(const float* __restrict__ q, const float* __restrict__ we,
                          const float* __restrict__ be, bf16* __restrict__ d0){
    __shared__ float qs[3200];
    for (int i = threadIdx.x; i < 3200; i += TPB) qs[i] = q[i];
    __syncthreads();
    int nidx = blockIdx.x*TPB + threadIdx.x;   // 32768
    float bias = be[nidx];
    float acc[32];
    #pragma unroll
    for (int bb = 0; bb < 32; ++bb) acc[bb] = bias;
    for (int k = 0; k < 100; ++k){
        float wv = we[(size_t)k*32768 + nidx];
        #pragma unroll
        for (int bb = 0; bb < 32; ++bb) acc[bb] = fmaf(qs[bb*100 + k], wv, acc[bb]);
    }
    #pragma unroll
    for (int bb = 0; bb < 32; ++bb) d0[bb*32768 + nidx] = __float2bfloat16(fmaxf(acc[bb], 0.f));
}

// ---- stride-2 conv_transpose (JAX SAME, no flip): ih = (oh+kh-2)/2 when even & >=0
template<int CI, int CO, bool SIG>
__global__ void kConvT2x(const bf16* __restrict__ x, const float* __restrict__ wT,
                         const float* __restrict__ b, bf16* __restrict__ y,
                         int IH, int IW, int total){
    int idx = blockIdx.x*TPB + threadIdx.x;
    if (idx >= total) return;
    int OW = IW*2, OH = IH*2;
    int co = idx % CO;
    int t  = idx / CO;
    int ow = t % OW; t /= OW;
    int oh = t % OH;
    int n  = t / OH;
    float acc = b[co];
    #pragma unroll
    for (int kh = 0; kh < 3; ++kh){
        int p = oh + kh - 2;
        if (p < 0 || (p & 1)) continue;
        int ih = p >> 1;
        #pragma unroll
        for (int kw = 0; kw < 3; ++kw){
            int pw = ow + kw - 2;
            if (pw < 0 || (pw & 1)) continue;
            int iw = pw >> 1;
            const bf162* x2 = reinterpret_cast<const bf162*>(x + ((size_t)(n*IH + ih)*IW + iw)*CI);
            const float2* w2 = reinterpret_cast<const float2*>(wT + ((kh*3 + kw)*CO + co)*CI);
            #pragma unroll
            for (int c = 0; c < CI/2; ++c){
                float2 xv = __bfloat1622float2(x2[c]);
                float2 wv = w2[c];
                acc = fmaf(xv.x, wv.x, acc);
                acc = fmaf(xv.y, wv.y, acc);
            }
        }
    }
    acc = SIG ? sigmoidf_(acc) : fmaxf(acc, 0.f);
    y[idx] = __float2bfloat16(acc);
}

// ---- convT3 stripe: d2[32,128,128,128] -> stripe rows [r0-1, r0+32] of d3 (sigmoid, bf16)
// stripe layout: [32][34][256][64], lr = oh - (r0-1)
__global__ void kConvT3s(const bf16* __restrict__ x, const float* __restrict__ wT,
                         const float* __restrict__ b, bf16* __restrict__ st, int r0){
    int idx = blockIdx.x*TPB + threadIdx.x;   // 32*34*256*64 = 17825792
    int co = idx & 63;
    int t  = idx >> 6;
    int ow = t & 255; t >>= 8;
    int lr = t % 34;
    int n  = t / 34;
    int oh = r0 - 1 + lr;
    if (oh < 0 || oh >= 256) return;
    float acc = b[co];
    #pragma unroll
    for (int kh = 0; kh < 3; ++kh){
        int p = oh + kh - 2;
        if (p < 0 || (p & 1)) continue;
        int ih = p >> 1;
        #pragma unroll
        for (int kw = 0; kw < 3; ++kw){
            int pw = ow + kw - 2;
            if (pw < 0 || (pw & 1)) continue;
            int iw = pw >> 1;
            const bf162* x2 = reinterpret_cast<const bf162*>(x + ((size_t)(n*128 + ih)*128 + iw)*128);
            const float2* w2 = reinterpret_cast<const float2*>(wT + ((kh*3 + kw)*64 + co)*128);
            #pragma unroll
            for (int c = 0; c < 64; ++c){
                float2 xv = __bfloat1622float2(x2[c]);
                float2 wv = w2[c];
                acc = fmaf(xv.x, wv.x, acc);
                acc = fmaf(xv.y, wv.y, acc);
            }
        }
    }
    st[idx] = __float2bfloat16(sigmoidf_(acc));
}

// ---- convT4 stripe: stripe(bf16) -> out rows [r0, r0+32), stride-1 SAME conv (pad 1,1), sigmoid
__global__ void kConvT4s(const bf16* __restrict__ st, const float* __restrict__ w,
                         const float* __restrict__ b, float* __restrict__ out, int r0){
    int idx = blockIdx.x*TPB + threadIdx.x;   // 32*32*256 = 262144
    int ow = idx & 255;
    int t  = idx >> 8;
    int rr = t & 31;
    int n  = t >> 5;
    int oh = r0 + rr;
    float acc = b[0];
    #pragma unroll
    for (int kh = 0; kh < 3; ++kh){
        int ih = oh + kh - 1; if (ih < 0 || ih >= 256) continue;
        int lr = ih - (r0 - 1);   // in [0,34)
        #pragma unroll
        for (int kw = 0; kw < 3; ++kw){
            int iw = ow + kw - 1; if (iw < 0 || iw >= 256) continue;
            const bf162* x2 = reinterpret_cast<const bf162*>(st + ((size_t)(n*34 + lr)*256 + iw)*64);
            const float* wp = w + (kh*3 + kw)*64;    // [3,3,64,1] -> ci contiguous
            #pragma unroll
            for (int c = 0; c < 32; ++c){
                float2 xv = __bfloat1622float2(x2[c]);
                acc = fmaf(xv.x, wp[2*c],   acc);
                acc = fmaf(xv.y, wp[2*c+1], acc);
            }
        }
    }
    out[((size_t)n*256 + oh)*256 + ow] = sigmoidf_(acc);
}

extern "C" void kernel_launch(void* const* d_in, const int* in_sizes, int n_in,
                              void* d_out, int out_size, void* d_ws, size_t ws_size,
                              hipStream_t stream){
    const float* x   = (const float*)d_in[0];
    const float* w1  = (const float*)d_in[1];
    const float* b1  = (const float*)d_in[2];
    const float* w2  = (const float*)d_in[3];
    const float* b2  = (const float*)d_in[4];
    const float* w3  = (const float*)d_in[5];
    const float* b3  = (const float*)d_in[6];
    const float* wd  = (const float*)d_in[7];
    const float* bd  = (const float*)d_in[8];
    const float* emb = (const float*)d_in[9];
    const float* we  = (const float*)d_in[10];
    const float* be  = (const float*)d_in[11];
    const float* wt1 = (const float*)d_in[12];
    const float* bt1 = (const float*)d_in[13];
    const float* wt2 = (const float*)d_in[14];
    const float* bt2 = (const float*)d_in[15];
    const float* wt3 = (const float*)d_in[16];
    const float* bt3 = (const float*)d_in[17];
    const float* wt4 = (const float*)d_in[18];
    const float* bt4 = (const float*)d_in[19];
    float* out = (float*)d_out;

    // Workspace plan (bf16 intermediates, striped d3). Peak ~226 MB.
    //  [0,2MB):     wT2, wT3, wTt1, wTt2, wTt3, z, q
    //  [2,36MB):    A: h1 -> h3 -> d1
    //  [36,53MB):   B: h2 -> d0
    //  [53,189MB):  d2 bf16 [32,128,128,128]
    //  [192,228MB): d3 stripe buffer [32,34,256,64] bf16
    char* ws = (char*)d_ws;
    const size_t MB = 1024*1024;
    float* wT2  = (float*)(ws);
    float* wT3  = (float*)(ws + 73728);
    float* wTt1 = (float*)(ws + 368640);
    float* wTt2 = (float*)(ws + 442368);
    float* wTt3 = (float*)(ws + 737280);
    float* z    = (float*)(ws + 1200*1024);
    float* q    = (float*)(ws + 1200*1024 + 16384);

    bf16* h1 = (bf16*)(ws + 2*MB);     // [32,128,128,32]
    bf16* h2 = (bf16*)(ws + 36*MB);    // [32,64,64,64]
    bf16* h3 = (bf16*)(ws + 2*MB);     // [32,32,32,128]
    bf16* d0 = (bf16*)(ws + 36*MB);    // [32,32,32,32]
    bf16* d1 = (bf16*)(ws + 2*MB);     // [32,64,64,64]
    bf16* d2 = (bf16*)(ws + 53*MB);    // [32,128,128,128]
    bf16* st = (bf16*)(ws + 192*MB);   // [32,34,256,64]

    // weight transposes (tiny)
    kTransposeW<<<(9*32*64 )/TPB, TPB, 0, stream>>>(w2,  wT2,  32, 64);
    kTransposeW<<<(9*64*128)/TPB, TPB, 0, stream>>>(w3,  wT3,  64, 128);
    kTransposeW<<<(9*32*64 )/TPB, TPB, 0, stream>>>(wt1, wTt1, 32, 64);
    kTransposeW<<<(9*64*128)/TPB, TPB, 0, stream>>>(wt2, wTt2, 64, 128);
    kTransposeW<<<(9*128*64)/TPB, TPB, 0, stream>>>(wt3, wTt3, 128, 64);

    // encoder
    kConv1<<<16777216/TPB, TPB, 0, stream>>>(x, w1, b1, h1);
    kConvS2<32,64><<<8388608/TPB, TPB, 0, stream>>>(h1, wT2, b2, h2, 128, 128, 64, 64, 8388608);
    kConvS2<64,128><<<4194304/TPB, TPB, 0, stream>>>(h2, wT3, b3, h3, 64, 64, 32, 32, 4194304);

    // dense + VQ
    kZero<<<(3200 + TPB-1)/TPB, TPB, 0, stream>>>(z, 3200);
    kDenseEnc<<<131072/KB, TPB, 0, stream>>>(h3, wd, z);
    kVQ<<<32, 128, 0, stream>>>(z, bd, emb, q);
    kDenseDec<<<32768/TPB, TPB, 0, stream>>>(q, we, be, d0);

    // decoder
    kConvT2x<32,64,false><<<8388608/TPB,   TPB, 0, stream>>>(d0, wTt1, bt1, d1, 32, 32, 8388608);
    kConvT2x<64,128,false><<<67108864/TPB, TPB, 0, stream>>>(d1, wTt2, bt2, d2, 64, 64, 67108864);

    // striped convT3 (sigmoid) + convT4 (sigmoid) -> out
    for (int s8 = 0; s8 < 8; ++s8){
        int r0 = s8 * 32;
        kConvT3s<<<17825792/TPB, TPB, 0, stream>>>(d2, wTt3, bt3, st, r0);
        kConvT4s<<<262144/TPB,   TPB, 0, stream>>>(st, wt4, bt4, out, r0);
    }
}

// Round 6
// 4703.221 us; speedup vs baseline: 5.8623x; 5.8623x over previous
//
#include <hip/hip_runtime.h>
#include <hip/hip_bf16.h>

#define TPB 256
typedef __hip_bfloat16 bf16;
typedef __attribute__((ext_vector_type(8))) unsigned short u16x8;

__device__ __forceinline__ float sigmoidf_(float v){ return 1.0f/(1.0f+expf(-v)); }
__device__ __forceinline__ float b2f(unsigned short u){ union{unsigned u32; float f;} v; v.u32 = ((unsigned)u)<<16; return v.f; }
__device__ __forceinline__ unsigned short f2b(float f){ unsigned x = __float_as_uint(f); return (unsigned short)((x + 0x7fffu + ((x>>16)&1u)) >> 16); }

// ---- conv1: x[32,256,256,1] f32 -> h1[32,128,128,32] bf16, stride 2 SAME(pad lo=0), relu
__global__ void kConv1(const float* __restrict__ x, const float* __restrict__ w,
                       const float* __restrict__ b, bf16* __restrict__ y){
    int idx = blockIdx.x*TPB + threadIdx.x;   // 16777216
    int co = idx & 31;
    int ow = (idx >> 5) & 127;
    int oh = (idx >> 12) & 127;
    int n  = idx >> 19;
    float acc = b[co];
    #pragma unroll
    for (int kh = 0; kh < 3; ++kh){
        int ih = oh*2 + kh; if (ih >= 256) break;
        #pragma unroll
        for (int kw = 0; kw < 3; ++kw){
            int iw = ow*2 + kw; if (iw >= 256) break;
            acc = fmaf(x[(n*256 + ih)*256 + iw], w[(kh*3 + kw)*32 + co], acc);
        }
    }
    y[idx] = __float2bfloat16(fmaxf(acc, 0.f));
}

// ---- forward stride-2 SAME conv (pad lo=0), relu.
// wave = one (n, oh) output row; lane = ow; weights [3,3,CI,CO] read as wave-uniform scalars.
template<int CI>
__global__ __launch_bounds__(TPB) void kConvF2(const bf16* __restrict__ x, const float* __restrict__ w,
        const float* __restrict__ b, bf16* __restrict__ y,
        int H, int W, int OH, int OW, int COF){
    int wid  = __builtin_amdgcn_readfirstlane(blockIdx.x*4 + (threadIdx.x>>6));
    int lane = threadIdx.x & 63;
    int oh = wid % OH;
    int n  = wid / OH;
    int co0 = blockIdx.y * 64;
    int ow = lane;
    bool act = (ow < OW);
    float acc[64];
    #pragma unroll
    for (int co = 0; co < 64; ++co) acc[co] = b[co0+co];
    for (int kh = 0; kh < 3; ++kh){
        int ih = 2*oh + kh; if (ih >= H) break;           // wave-uniform
        const bf16* xrow = x + (size_t)(n*H + ih)*W*CI;
        for (int kw = 0; kw < 3; ++kw){
            int iw = 2*ow + kw;
            bool valid = act && (iw < W);                 // per-lane only at right edge
            const float* wrow = w + (size_t)(kh*3 + kw)*CI*COF + co0;
            #pragma unroll 1
            for (int ci8 = 0; ci8 < CI/8; ++ci8){
                u16x8 xr = {};
                if (valid) xr = *reinterpret_cast<const u16x8*>(xrow + (size_t)iw*CI + ci8*8);
                #pragma unroll
                for (int c = 0; c < 8; ++c){
                    float xf = b2f(xr[c]);
                    const float* wp = wrow + (size_t)(ci8*8 + c)*COF;
                    #pragma unroll
                    for (int co = 0; co < 64; ++co)
                        acc[co] = fmaf(xf, wp[co], acc[co]);   // wp[co] wave-uniform -> s_load
                }
            }
        }
    }
    if (act){
        bf16* yp = y + ((size_t)(n*OH + oh)*OW + ow)*COF + co0;
        #pragma unroll
        for (int g = 0; g < 8; ++g){
            u16x8 t;
            #pragma unroll
            for (int c = 0; c < 8; ++c) t[c] = f2b(fmaxf(acc[g*8+c], 0.f));
            *reinterpret_cast<u16x8*>(yp + g*8) = t;
        }
    }
}

// ---- stride-2 conv_transpose (JAX SAME, no flip), parity-class mapped.
// wave = (n, output row oh, dx class, j-block); lane = j (input col for this class).
// waves total = NJB * 2 * OHR * N.
template<int CI>
__global__ __launch_bounds__(TPB) void kConvTP(const bf16* __restrict__ x, const float* __restrict__ w,
        const float* __restrict__ b, bf16* __restrict__ y,
        int IH, int IW, int NJB, int OHR, int ohBase, int OHFULL, int COF, int doSig){
    int wid  = __builtin_amdgcn_readfirstlane(blockIdx.x*4 + (threadIdx.x>>6));
    int lane = threadIdx.x & 63;
    int jblk = wid % NJB; int rest = wid / NJB;
    int dx = rest & 1; rest >>= 1;
    int ohl = rest % OHR;
    int n   = rest / OHR;
    int oh  = ohBase + ohl;
    if (oh < 0 || oh >= OHFULL) return;                   // wave-uniform
    int co0 = blockIdx.y * 64;
    int j = jblk*64 + lane;
    bool act = (j < IW);
    int OW = IW*2;
    int ow = 2*j + dx;
    int dy = oh & 1;
    int i  = oh >> 1;
    bool hasK0 = (dy == 0) && (i >= 1);
    int nkh = (dy == 0) ? (hasK0 ? 2 : 1) : 1;
    float acc[64];
    #pragma unroll
    for (int co = 0; co < 64; ++co) acc[co] = b[co0+co];
    for (int a = 0; a < nkh; ++a){
        int kh, ih;
        if (dy == 1){ kh = 1; ih = i; }
        else if (hasK0 && a == 0){ kh = 0; ih = i - 1; }
        else { kh = 2; ih = i; }
        const bf16* xrow = x + (size_t)(n*IH + ih)*IW*CI;
        int nkw = (dx == 0) ? 2 : 1;
        for (int e = 0; e < nkw; ++e){
            int kw, iw; bool valid = act;
            if (dx == 0){
                if (e == 0){ kw = 0; iw = j - 1; valid = act && (j >= 1); }
                else       { kw = 2; iw = j; }
            } else { kw = 1; iw = j; }
            const float* wrow = w + (size_t)(kh*3 + kw)*CI*COF + co0;
            #pragma unroll 1
            for (int ci8 = 0; ci8 < CI/8; ++ci8){
                u16x8 xr = {};
                if (valid) xr = *reinterpret_cast<const u16x8*>(xrow + (size_t)iw*CI + ci8*8);
                #pragma unroll
                for (int c = 0; c < 8; ++c){
                    float xf = b2f(xr[c]);
                    const float* wp = wrow + (size_t)(ci8*8 + c)*COF;
                    #pragma unroll
                    for (int co = 0; co < 64; ++co)
                        acc[co] = fmaf(xf, wp[co], acc[co]);
                }
            }
        }
    }
    if (act){
        bf16* yp = y + (((size_t)n*OHR + ohl)*OW + ow)*COF + co0;
        #pragma unroll
        for (int g = 0; g < 8; ++g){
            u16x8 t;
            #pragma unroll
            for (int c = 0; c < 8; ++c){
                float v = acc[g*8+c];
                v = doSig ? sigmoidf_(v) : fmaxf(v, 0.f);
                t[c] = f2b(v);
            }
            *reinterpret_cast<u16x8*>(yp + g*8) = t;
        }
    }
}

// ---- final convT4 (stride 1, CO=1): wave per output pixel, lanes = 64 ci (coalesced), shfl-reduce.
__global__ __launch_bounds__(TPB) void kConvO(const bf16* __restrict__ st, const float* __restrict__ w,
        const float* __restrict__ b, float* __restrict__ out, int r0){
    int wid  = __builtin_amdgcn_readfirstlane(blockIdx.x*4 + (threadIdx.x>>6));
    int lane = threadIdx.x & 63;
    int ow = wid & 255; int t = wid >> 8; int rr = t & 31; int n = t >> 5;
    int oh = r0 + rr;
    const unsigned short* stp = (const unsigned short*)st;
    float acc = 0.f;
    #pragma unroll
    for (int kh = 0; kh < 3; ++kh){
        int ih = oh + kh - 1; if (ih < 0 || ih >= 256) continue;
        int lr = ih - (r0 - 1);                            // stripe-local row in [0,34)
        #pragma unroll
        for (int kw = 0; kw < 3; ++kw){
            int iw = ow + kw - 1; if (iw < 0 || iw >= 256) continue;
            float xv = b2f(stp[(((size_t)n*34 + lr)*256 + iw)*64 + lane]);
            acc = fmaf(xv, w[(kh*3 + kw)*64 + lane], acc);
        }
    }
    #pragma unroll
    for (int off = 32; off > 0; off >>= 1) acc += __shfl_down(acc, off, 64);
    if (lane == 0) out[((size_t)n*256 + oh)*256 + ow] = sigmoidf_(acc + b[0]);
}

__global__ void kZero(float* __restrict__ p, int n){
    int i = blockIdx.x*TPB + threadIdx.x;
    if (i < n) p[i] = 0.f;
}

// ---- encoder dense: z[32,100] += h3[32,131072](bf16) @ wd[131072,100]
#define KB 256
__global__ void kDenseEnc(const bf16* __restrict__ h, const float* __restrict__ wd,
                          float* __restrict__ z){
    __shared__ float hs[32][KB];
    int k0 = blockIdx.x * KB;
    for (int i = threadIdx.x; i < 32*KB; i += TPB){
        int bb = i >> 8;
        int kk = i & (KB-1);
        hs[bb][kk] = __bfloat162float(h[bb*131072 + k0 + kk]);
    }
    __syncthreads();
    int j = threadIdx.x;
    if (j < 100){
        float acc[32];
        #pragma unroll
        for (int bb = 0; bb < 32; ++bb) acc[bb] = 0.f;
        for (int kk = 0; kk < KB; ++kk){
            float wv = wd[(size_t)(k0 + kk)*100 + j];
            #pragma unroll
            for (int bb = 0; bb < 32; ++bb) acc[bb] = fmaf(hs[bb][kk], wv, acc[bb]);
        }
        #pragma unroll
        for (int bb = 0; bb < 32; ++bb) atomicAdd(&z[bb*100 + j], acc[bb]);
    }
}

// ---- VQ: q[b] = emb[argmin_k ||z[b]+bd - emb[k]||^2], first-min-wins
__global__ void kVQ(const float* __restrict__ z, const float* __restrict__ bd,
                    const float* __restrict__ emb, float* __restrict__ q){
    __shared__ float zb[100];
    __shared__ float d2s[128];
    __shared__ int best;
    int b = blockIdx.x;
    int t = threadIdx.x;
    if (t < 100) zb[t] = z[b*100 + t] + bd[t];
    __syncthreads();
    if (t < 100){
        float acc = 0.f;
        for (int d = 0; d < 100; ++d){
            float df = zb[d] - emb[t*100 + d];
            acc = fmaf(df, df, acc);
        }
        d2s[t] = acc;
    }
    __syncthreads();
    if (t == 0){
        float m = d2s[0]; int mi = 0;
        for (int k = 1; k < 100; ++k){ if (d2s[k] < m){ m = d2s[k]; mi = k; } }
        best = mi;
    }
    __syncthreads();
    if (t < 100) q[b*100 + t] = emb[best*100 + t];
}

// ---- decoder dense: d0[32,32768] = relu(q @ we + be), bf16 out
__global__ void kDenseDec(const float* __restrict__ q, const float* __restrict__ we,
                          const float* __restrict__ be, bf16* __restrict__ d0){
    __shared__ float qs[3200];
    for (int i = threadIdx.x; i < 3200; i += TPB) qs[i] = q[i];
    __syncthreads();
    int nidx = blockIdx.x*TPB + threadIdx.x;
    float bias = be[nidx];
    float acc[32];
    #pragma unroll
    for (int bb = 0; bb < 32; ++bb) acc[bb] = bias;
    for (int k = 0; k < 100; ++k){
        float wv = we[(size_t)k*32768 + nidx];
        #pragma unroll
        for (int bb = 0; bb < 32; ++bb) acc[bb] = fmaf(qs[bb*100 + k], wv, acc[bb]);
    }
    #pragma unroll
    for (int bb = 0; bb < 32; ++bb) d0[bb*32768 + nidx] = __float2bfloat16(fmaxf(acc[bb], 0.f));
}

extern "C" void kernel_launch(void* const* d_in, const int* in_sizes, int n_in,
                              void* d_out, int out_size, void* d_ws, size_t ws_size,
                              hipStream_t stream){
    const float* x   = (const float*)d_in[0];
    const float* w1  = (const float*)d_in[1];
    const float* b1  = (const float*)d_in[2];
    const float* w2  = (const float*)d_in[3];
    const float* b2  = (const float*)d_in[4];
    const float* w3  = (const float*)d_in[5];
    const float* b3  = (const float*)d_in[6];
    const float* wd  = (const float*)d_in[7];
    const float* bd  = (const float*)d_in[8];
    const float* emb = (const float*)d_in[9];
    const float* we  = (const float*)d_in[10];
    const float* be  = (const float*)d_in[11];
    const float* wt1 = (const float*)d_in[12];
    const float* bt1 = (const float*)d_in[13];
    const float* wt2 = (const float*)d_in[14];
    const float* bt2 = (const float*)d_in[15];
    const float* wt3 = (const float*)d_in[16];
    const float* bt3 = (const float*)d_in[17];
    const float* wt4 = (const float*)d_in[18];
    const float* bt4 = (const float*)d_in[19];
    float* out = (float*)d_out;

    // Workspace (peak ~228 MB):
    //  [0,1MB): z,q   [2,36MB): A(h1->h3->d1)   [36,53MB): B(h2->d0)
    //  [53,189MB): d2 bf16 [32,128,128,128]     [192,228MB): stripe [32,34,256,64] bf16
    char* ws = (char*)d_ws;
    const size_t MB = 1024*1024;
    float* z = (float*)(ws);
    float* q = (float*)(ws + 16384);
    bf16* h1 = (bf16*)(ws + 2*MB);
    bf16* h2 = (bf16*)(ws + 36*MB);
    bf16* h3 = (bf16*)(ws + 2*MB);
    bf16* d0 = (bf16*)(ws + 36*MB);
    bf16* d1 = (bf16*)(ws + 2*MB);
    bf16* d2 = (bf16*)(ws + 53*MB);
    bf16* st = (bf16*)(ws + 192*MB);

    // encoder
    kConv1<<<65536, TPB, 0, stream>>>(x, w1, b1, h1);
    kConvF2<32><<<dim3(512,1),  TPB, 0, stream>>>(h1, w2, b2, h2, 128, 128, 64, 64, 64);   // waves 2048 = 32*64
    kConvF2<64><<<dim3(256,2),  TPB, 0, stream>>>(h2, w3, b3, h3, 64, 64, 32, 32, 128);    // waves 1024 = 32*32

    // dense + VQ
    kZero<<<13, TPB, 0, stream>>>(z, 3200);
    kDenseEnc<<<131072/KB, TPB, 0, stream>>>(h3, wd, z);
    kVQ<<<32, 128, 0, stream>>>(z, bd, emb, q);
    kDenseDec<<<32768/TPB, TPB, 0, stream>>>(q, we, be, d0);

    // decoder
    // convT1: waves = NJB*2*OHR*N = 1*2*64*32 = 4096
    kConvTP<32><<<dim3(1024,1), TPB, 0, stream>>>(d0, wt1, bt1, d1, 32, 32, 1, 64, 0, 64, 64, 0);
    // convT2: waves = 1*2*128*32 = 8192; co chunks = 2
    kConvTP<64><<<dim3(2048,2), TPB, 0, stream>>>(d1, wt2, bt2, d2, 64, 64, 1, 128, 0, 128, 128, 0);

    // convT3 (sigmoid) striped into 8x 34-row halo stripes + final convT4
    for (int s8 = 0; s8 < 8; ++s8){
        int r0 = s8 * 32;
        // waves = NJB*2*OHR*N = 2*2*34*32 = 4352 -> grid.x = 1088  (round-4 bug: was 2176 -> OOB)
        kConvTP<128><<<dim3(1088,1), TPB, 0, stream>>>(d2, wt3, bt3, st, 128, 128, 2, 34, r0-1, 256, 64, 1);
        // waves = 32*32*256 = 262144
        kConvO<<<65536, TPB, 0, stream>>>(st, wt4, bt4, out, r0);
    }
}

// Round 7
// 1178.100 us; speedup vs baseline: 23.4036x; 3.9922x over previous
//
#include <hip/hip_runtime.h>
#include <hip/hip_bf16.h>

#define TPB 256
typedef __hip_bfloat16 bf16;
typedef __attribute__((ext_vector_type(8))) short short8;
typedef __attribute__((ext_vector_type(4))) float f32x4;

__device__ __forceinline__ float sigmoidf_(float v){ return 1.0f/(1.0f+__expf(-v)); }
__device__ __forceinline__ float b2f(unsigned short u){ union{unsigned u32; float f;} v; v.u32 = ((unsigned)u)<<16; return v.f; }

// ======== tap/class plumbing ========
struct ClassArg {
    int ntap;
    int taps[9];    // packed: tapIdx*16 + (offh+1)*4 + (offw+1)
    int ohBase;     // absolute logical row = ohBase + row
    int drow;       // output row = rowAbs*SROW + drow
    int dcol;       // output col = col*SCOL + dcol
};
struct ConvArgs { ClassArg cls[4]; };

// ======== weight prep: [3,3,CI,CO] f32 -> [9,CO,CI] bf16 ========
__global__ void kPrepW(const float* __restrict__ w, bf16* __restrict__ wT, int CI, int CO){
    int idx = blockIdx.x*TPB + threadIdx.x;
    if (idx >= 9*CI*CO) return;
    int ci = idx % CI;
    int co = (idx / CI) % CO;
    int tp = idx / (CI*CO);
    wT[idx] = __float2bfloat16(w[(tp*CI + ci)*CO + co]);
}

// ======== conv1: x[32,256,256,1] f32 -> h1[32,128,128,32] bf16, stride2 SAME, relu ========
__global__ void kConv1(const float* __restrict__ x, const float* __restrict__ w,
                       const float* __restrict__ b, bf16* __restrict__ y){
    int idx = blockIdx.x*TPB + threadIdx.x;   // 16777216
    int co = idx & 31;
    int ow = (idx >> 5) & 127;
    int oh = (idx >> 12) & 127;
    int n  = idx >> 19;
    float acc = b[co];
    #pragma unroll
    for (int kh = 0; kh < 3; ++kh){
        int ih = oh*2 + kh; if (ih >= 256) break;
        #pragma unroll
        for (int kw = 0; kw < 3; ++kw){
            int iw = ow*2 + kw; if (iw >= 256) break;
            acc = fmaf(x[(n*256 + ih)*256 + iw], w[(kh*3 + kw)*32 + co], acc);
        }
    }
    y[idx] = __float2bfloat16(fmaxf(acc, 0.f));
}

// ======== unified MFMA implicit-GEMM conv ========
// wave = 64 M-rows x 64 co. m-space: per n, MROWS logical rows x OWT cols.
// S2: ih = 2*rowAbs + offh (forward);  !S2: ih = rowAbs + offh (transpose parity class).
// Output: row = rowAbs*SROW + drow, col = col*SCOL + dcol.  ACT: 0 relu, 1 sigmoid.
template<int CI, bool S2, int ACT, int SROW, int SCOL, int OWT, int MROWS, int MAXT>
__global__ __launch_bounds__(TPB) void kConvMM(
    const bf16* __restrict__ x, const bf16* __restrict__ wT,
    const float* __restrict__ bias, bf16* __restrict__ y,
    int H, int W, int validRows, int CO, int OHout, int OWout,
    ConvArgs ca)
{
    constexpr int KC = CI/32;
    constexpr int PERN = MROWS*OWT;
    const ClassArg cl = ca.cls[blockIdx.z];
    int wid  = blockIdx.x*4 + (threadIdx.x>>6);
    int lane = threadIdx.x & 63;
    int lrow = lane & 15;     // A-row / B-col / D-col within fragment
    int kgrp = lane >> 4;     // K-group (8 elems each)
    int m0 = wid*64;
    int co0 = blockIdx.y*64;

    // per-mi decode of A rows (m = m0 + mi*16 + lrow)
    const bf16* pBase[4]; int rowS[4], colS[4]; bool mact[4];
    #pragma unroll
    for (int mi = 0; mi < 4; ++mi){
        int m = m0 + mi*16 + lrow;
        int n = m / PERN;
        int rem = m - n*PERN;
        int row = rem / OWT;
        int col = rem - row*OWT;
        int rAbs = cl.ohBase + row;
        mact[mi] = ((unsigned)rAbs < (unsigned)validRows);
        rowS[mi] = S2 ? 2*rAbs : rAbs;
        colS[mi] = S2 ? 2*col : col;
        pBase[mi] = x + (size_t)n*H*W*CI + ((size_t)rowS[mi]*W + colS[mi])*CI + kgrp*8;
    }

    f32x4 acc[4][4];
    #pragma unroll
    for (int mi = 0; mi < 4; ++mi)
        #pragma unroll
        for (int ni = 0; ni < 4; ++ni)
            acc[mi][ni] = (f32x4){0.f, 0.f, 0.f, 0.f};

    const short8 zero8 = {0,0,0,0,0,0,0,0};

    #pragma unroll
    for (int t = 0; t < MAXT; ++t){
        if (t >= cl.ntap) break;
        int pk = cl.taps[t];
        int tap = pk >> 4;
        int offh = ((pk>>2)&3) - 1;
        int offw = (pk&3) - 1;
        const bf16* wtp = wT + ((size_t)tap*CO + co0 + lrow)*CI + kgrp*8;
        const bf16* pA[4]; bool vA[4];
        int doff = offh*W + offw;                       // wave-uniform
        #pragma unroll
        for (int mi = 0; mi < 4; ++mi){
            int ih = rowS[mi] + offh;
            int iw = colS[mi] + offw;
            vA[mi] = mact[mi] && ((unsigned)ih < (unsigned)H) && ((unsigned)iw < (unsigned)W);
            pA[mi] = pBase[mi] + (ptrdiff_t)doff*CI;
        }
        #pragma unroll
        for (int kc = 0; kc < KC; ++kc){
            short8 b0 = *(const short8*)(wtp + (size_t)0*16*CI + kc*32);
            short8 b1 = *(const short8*)(wtp + (size_t)1*16*CI + kc*32);
            short8 b2 = *(const short8*)(wtp + (size_t)2*16*CI + kc*32);
            short8 b3 = *(const short8*)(wtp + (size_t)3*16*CI + kc*32);
            short8 a0 = vA[0] ? *(const short8*)(pA[0] + kc*32) : zero8;
            short8 a1 = vA[1] ? *(const short8*)(pA[1] + kc*32) : zero8;
            short8 a2 = vA[2] ? *(const short8*)(pA[2] + kc*32) : zero8;
            short8 a3 = vA[3] ? *(const short8*)(pA[3] + kc*32) : zero8;
            acc[0][0] = __builtin_amdgcn_mfma_f32_16x16x32_bf16(a0, b0, acc[0][0], 0, 0, 0);
            acc[0][1] = __builtin_amdgcn_mfma_f32_16x16x32_bf16(a0, b1, acc[0][1], 0, 0, 0);
            acc[0][2] = __builtin_amdgcn_mfma_f32_16x16x32_bf16(a0, b2, acc[0][2], 0, 0, 0);
            acc[0][3] = __builtin_amdgcn_mfma_f32_16x16x32_bf16(a0, b3, acc[0][3], 0, 0, 0);
            acc[1][0] = __builtin_amdgcn_mfma_f32_16x16x32_bf16(a1, b0, acc[1][0], 0, 0, 0);
            acc[1][1] = __builtin_amdgcn_mfma_f32_16x16x32_bf16(a1, b1, acc[1][1], 0, 0, 0);
            acc[1][2] = __builtin_amdgcn_mfma_f32_16x16x32_bf16(a1, b2, acc[1][2], 0, 0, 0);
            acc[1][3] = __builtin_amdgcn_mfma_f32_16x16x32_bf16(a1, b3, acc[1][3], 0, 0, 0);
            acc[2][0] = __builtin_amdgcn_mfma_f32_16x16x32_bf16(a2, b0, acc[2][0], 0, 0, 0);
            acc[2][1] = __builtin_amdgcn_mfma_f32_16x16x32_bf16(a2, b1, acc[2][1], 0, 0, 0);
            acc[2][2] = __builtin_amdgcn_mfma_f32_16x16x32_bf16(a2, b2, acc[2][2], 0, 0, 0);
            acc[2][3] = __builtin_amdgcn_mfma_f32_16x16x32_bf16(a2, b3, acc[2][3], 0, 0, 0);
            acc[3][0] = __builtin_amdgcn_mfma_f32_16x16x32_bf16(a3, b0, acc[3][0], 0, 0, 0);
            acc[3][1] = __builtin_amdgcn_mfma_f32_16x16x32_bf16(a3, b1, acc[3][1], 0, 0, 0);
            acc[3][2] = __builtin_amdgcn_mfma_f32_16x16x32_bf16(a3, b2, acc[3][2], 0, 0, 0);
            acc[3][3] = __builtin_amdgcn_mfma_f32_16x16x32_bf16(a3, b3, acc[3][3], 0, 0, 0);
        }
    }

    // epilogue: bias + activation + store. D row = m0+mi*16+kgrp*4+r, D col = co0+ni*16+lrow.
    float bv[4];
    #pragma unroll
    for (int ni = 0; ni < 4; ++ni) bv[ni] = bias[co0 + ni*16 + lrow];
    #pragma unroll
    for (int mi = 0; mi < 4; ++mi){
        int m = m0 + mi*16 + kgrp*4;
        int n = m / PERN;
        int rem = m - n*PERN;
        int row = rem / OWT;
        int col = rem - row*OWT;          // col..col+3 within a row (4 | OWT)
        int rAbs = cl.ohBase + row;
        if ((unsigned)rAbs >= (unsigned)validRows) continue;
        int ohp = rAbs*SROW + cl.drow;
        int owp = col*SCOL + cl.dcol;
        bf16* yp = y + (((size_t)n*OHout + ohp)*OWout + owp)*CO + co0 + lrow;
        #pragma unroll
        for (int r = 0; r < 4; ++r){
            #pragma unroll
            for (int ni = 0; ni < 4; ++ni){
                float v = acc[mi][ni][r] + bv[ni];
                v = (ACT == 1) ? sigmoidf_(v) : fmaxf(v, 0.f);
                yp[(size_t)r*SCOL*CO + ni*16] = __float2bfloat16(v);
            }
        }
    }
}

// ======== final convT4 (stride1, CO=1): wave = 4 output pixels, lanes = 64 ci ========
__global__ __launch_bounds__(TPB) void kConvO4(const bf16* __restrict__ st, const float* __restrict__ w,
        const float* __restrict__ b, float* __restrict__ out, int r0){
    int wid  = blockIdx.x*4 + (threadIdx.x>>6);   // 65536 waves
    int lane = threadIdx.x & 63;
    int ow4 = (wid & 63)*4;
    int t = wid >> 6; int rr = t & 31; int n = t >> 5;
    int oh = r0 + rr;
    const unsigned short* stp = (const unsigned short*)st;
    float w9[9];
    #pragma unroll
    for (int k = 0; k < 9; ++k) w9[k] = w[k*64 + lane];
    float a0=0.f, a1=0.f, a2=0.f, a3=0.f;
    #pragma unroll
    for (int kh = 0; kh < 3; ++kh){
        int ih = oh + kh - 1; if (ih < 0 || ih >= 256) continue;
        int lr = ih - (r0 - 1);                     // stripe-local row [0,34)
        const unsigned short* rp = stp + (((size_t)n*34 + lr)*256)*64 + lane;
        #pragma unroll
        for (int c = 0; c < 6; ++c){
            int iw = ow4 - 1 + c;
            if ((unsigned)iw >= 256u) continue;
            float xv = b2f(rp[(size_t)iw*64]);
            if (c-0 >= 0 && c-0 < 3) a0 = fmaf(xv, w9[kh*3 + (c-0)], a0);
            if (c-1 >= 0 && c-1 < 3) a1 = fmaf(xv, w9[kh*3 + (c-1)], a1);
            if (c-2 >= 0 && c-2 < 3) a2 = fmaf(xv, w9[kh*3 + (c-2)], a2);
            if (c-3 >= 0 && c-3 < 3) a3 = fmaf(xv, w9[kh*3 + (c-3)], a3);
        }
    }
    #pragma unroll
    for (int off = 32; off > 0; off >>= 1){
        a0 += __shfl_down(a0, off, 64);
        a1 += __shfl_down(a1, off, 64);
        a2 += __shfl_down(a2, off, 64);
        a3 += __shfl_down(a3, off, 64);
    }
    if (lane == 0){
        float bb = b[0];
        float* op = out + ((size_t)n*256 + oh)*256 + ow4;
        op[0] = sigmoidf_(a0 + bb);
        op[1] = sigmoidf_(a1 + bb);
        op[2] = sigmoidf_(a2 + bb);
        op[3] = sigmoidf_(a3 + bb);
    }
}

__global__ void kZero(float* __restrict__ p, int n){
    int i = blockIdx.x*TPB + threadIdx.x;
    if (i < n) p[i] = 0.f;
}

// ======== encoder dense: z[32,100] += h3[32,131072](bf16) @ wd[131072,100] ========
#define KB 256
__global__ void kDenseEnc(const bf16* __restrict__ h, const float* __restrict__ wd,
                          float* __restrict__ z){
    __shared__ float hs[32][KB];
    int k0 = blockIdx.x * KB;
    for (int i = threadIdx.x; i < 32*KB; i += TPB){
        int bb = i >> 8;
        int kk = i & (KB-1);
        hs[bb][kk] = __bfloat162float(h[bb*131072 + k0 + kk]);
    }
    __syncthreads();
    int j = threadIdx.x;
    if (j < 100){
        float acc[32];
        #pragma unroll
        for (int bb = 0; bb < 32; ++bb) acc[bb] = 0.f;
        for (int kk = 0; kk < KB; ++kk){
            float wv = wd[(size_t)(k0 + kk)*100 + j];
            #pragma unroll
            for (int bb = 0; bb < 32; ++bb) acc[bb] = fmaf(hs[bb][kk], wv, acc[bb]);
        }
        #pragma unroll
        for (int bb = 0; bb < 32; ++bb) atomicAdd(&z[bb*100 + j], acc[bb]);
    }
}

// ======== VQ ========
__global__ void kVQ(const float* __restrict__ z, const float* __restrict__ bd,
                    const float* __restrict__ emb, float* __restrict__ q){
    __shared__ float zb[100];
    __shared__ float d2s[128];
    __shared__ int best;
    int b = blockIdx.x;
    int t = threadIdx.x;
    if (t < 100) zb[t] = z[b*100 + t] + bd[t];
    __syncthreads();
    if (t < 100){
        float acc = 0.f;
        for (int d = 0; d < 100; ++d){
            float df = zb[d] - emb[t*100 + d];
            acc = fmaf(df, df, acc);
        }
        d2s[t] = acc;
    }
    __syncthreads();
    if (t == 0){
        float m = d2s[0]; int mi = 0;
        for (int k = 1; k < 100; ++k){ if (d2s[k] < m){ m = d2s[k]; mi = k; } }
        best = mi;
    }
    __syncthreads();
    if (t < 100) q[b*100 + t] = emb[best*100 + t];
}

// ======== decoder dense ========
__global__ void kDenseDec(const float* __restrict__ q, const float* __restrict__ we,
                          const float* __restrict__ be, bf16* __restrict__ d0){
    __shared__ float qs[3200];
    for (int i = threadIdx.x; i < 3200; i += TPB) qs[i] = q[i];
    __syncthreads();
    int nidx = blockIdx.x*TPB + threadIdx.x;
    float bias = be[nidx];
    float acc[32];
    #pragma unroll
    for (int bb = 0; bb < 32; ++bb) acc[bb] = bias;
    for (int k = 0; k < 100; ++k){
        float wv = we[(size_t)k*32768 + nidx];
        #pragma unroll
        for (int bb = 0; bb < 32; ++bb) acc[bb] = fmaf(qs[bb*100 + k], wv, acc[bb]);
    }
    #pragma unroll
    for (int bb = 0; bb < 32; ++bb) d0[bb*32768 + nidx] = __float2bfloat16(fmaxf(acc[bb], 0.f));
}

// ======== host-side tap builders ========
static ClassArg mkTransCls(int dy, int dx, int ohBase, int drow){
    ClassArg c{};
    c.ohBase = ohBase; c.drow = drow; c.dcol = dx; c.ntap = 0;
    int khs[2], ohs[2], nk = 0;
    if (dy == 0){ khs[0]=0; ohs[0]=-1; khs[1]=2; ohs[1]=0; nk=2; }
    else        { khs[0]=1; ohs[0]=0; nk=1; }
    int kws[2], ows[2], nw = 0;
    if (dx == 0){ kws[0]=0; ows[0]=-1; kws[1]=2; ows[1]=0; nw=2; }
    else        { kws[0]=1; ows[0]=0; nw=1; }
    for (int a = 0; a < nk; ++a)
        for (int e = 0; e < nw; ++e)
            c.taps[c.ntap++] = (khs[a]*3 + kws[e])*16 + (ohs[a]+1)*4 + (ows[e]+1);
    return c;
}
static ConvArgs mkFwdArgs(){
    ConvArgs ca{};
    ca.cls[0].ntap = 9; ca.cls[0].ohBase = 0; ca.cls[0].drow = 0; ca.cls[0].dcol = 0;
    for (int kh = 0; kh < 3; ++kh)
        for (int kw = 0; kw < 3; ++kw)
            ca.cls[0].taps[kh*3+kw] = (kh*3+kw)*16 + (kh+1)*4 + (kw+1);
    return ca;
}
static ConvArgs mkTransArgs(){
    ConvArgs ca{};
    for (int dy = 0; dy < 2; ++dy)
        for (int dx = 0; dx < 2; ++dx)
            ca.cls[dy*2+dx] = mkTransCls(dy, dx, 0, dy);
    return ca;
}

extern "C" void kernel_launch(void* const* d_in, const int* in_sizes, int n_in,
                              void* d_out, int out_size, void* d_ws, size_t ws_size,
                              hipStream_t stream){
    const float* x   = (const float*)d_in[0];
    const float* w1  = (const float*)d_in[1];
    const float* b1  = (const float*)d_in[2];
    const float* w2  = (const float*)d_in[3];
    const float* b2  = (const float*)d_in[4];
    const float* w3  = (const float*)d_in[5];
    const float* b3  = (const float*)d_in[6];
    const float* wd  = (const float*)d_in[7];
    const float* bd  = (const float*)d_in[8];
    const float* emb = (const float*)d_in[9];
    const float* we  = (const float*)d_in[10];
    const float* be  = (const float*)d_in[11];
    const float* wt1 = (const float*)d_in[12];
    const float* bt1 = (const float*)d_in[13];
    const float* wt2 = (const float*)d_in[14];
    const float* bt2 = (const float*)d_in[15];
    const float* wt3 = (const float*)d_in[16];
    const float* bt3 = (const float*)d_in[17];
    const float* wt4 = (const float*)d_in[18];
    const float* bt4 = (const float*)d_in[19];
    float* out = (float*)d_out;

    // Workspace (peak ~228 MB):
    //  [0,2MB): z, q, bf16 wT buffers
    //  [2,36MB): A(h1->h3->d1)   [36,53MB): B(h2->d0)
    //  [53,189MB): d2 bf16 [32,128,128,128]   [192,228MB): stripe [32,34,256,64] bf16
    char* ws = (char*)d_ws;
    const size_t MB = 1024*1024;
    float* z = (float*)(ws);
    float* q = (float*)(ws + 16384);
    bf16* wT2  = (bf16*)(ws + 512*1024);    // 9*64*32  = 18432 el (36 KB)
    bf16* wT3  = (bf16*)(ws + 768*1024);    // 9*128*64 = 73728 el (144 KB)
    bf16* wTt1 = (bf16*)(ws + 1024*1024);   // 18432 el
    bf16* wTt2 = (bf16*)(ws + 1280*1024);   // 73728 el
    bf16* wTt3 = (bf16*)(ws + 1536*1024);   // 9*64*128 = 73728 el
    bf16* h1 = (bf16*)(ws + 2*MB);
    bf16* h2 = (bf16*)(ws + 36*MB);
    bf16* h3 = (bf16*)(ws + 2*MB);
    bf16* d0 = (bf16*)(ws + 36*MB);
    bf16* d1 = (bf16*)(ws + 2*MB);
    bf16* d2 = (bf16*)(ws + 53*MB);
    bf16* st = (bf16*)(ws + 192*MB);

    // weight prep
    kPrepW<<<(9*32*64 + TPB-1)/TPB, TPB, 0, stream>>>(w2,  wT2,  32, 64);
    kPrepW<<<(9*64*128+ TPB-1)/TPB, TPB, 0, stream>>>(w3,  wT3,  64, 128);
    kPrepW<<<(9*32*64 + TPB-1)/TPB, TPB, 0, stream>>>(wt1, wTt1, 32, 64);
    kPrepW<<<(9*64*128+ TPB-1)/TPB, TPB, 0, stream>>>(wt2, wTt2, 64, 128);
    kPrepW<<<(9*128*64+ TPB-1)/TPB, TPB, 0, stream>>>(wt3, wTt3, 128, 64);

    ConvArgs fwd = mkFwdArgs();
    ConvArgs trs = mkTransArgs();

    // encoder
    kConv1<<<65536, TPB, 0, stream>>>(x, w1, b1, h1);
    // conv2: h1[32,128,128,32] -> h2[32,64,64,64]; M=131072 -> 2048 tiles -> 512 blocks
    kConvMM<32, true, 0, 1, 1, 64, 64, 9><<<dim3(512,1,1), TPB, 0, stream>>>(
        h1, wT2, b2, h2, 128, 128, 64, 64, 64, 64, fwd);
    // conv3: h2 -> h3[32,32,32,128]; M=32768 -> 512 tiles -> 128 blocks, co chunks 2
    kConvMM<64, true, 0, 1, 1, 32, 32, 9><<<dim3(128,2,1), TPB, 0, stream>>>(
        h2, wT3, b3, h3, 64, 64, 32, 128, 32, 32, fwd);

    // dense + VQ
    kZero<<<13, TPB, 0, stream>>>(z, 3200);
    kDenseEnc<<<131072/KB, TPB, 0, stream>>>(h3, wd, z);
    kVQ<<<32, 128, 0, stream>>>(z, bd, emb, q);
    kDenseDec<<<32768/TPB, TPB, 0, stream>>>(q, we, be, d0);

    // decoder
    // convT1: d0[32,32,32,32] -> d1[32,64,64,64]; M=32768/class -> 128 blocks, z=4
    kConvMM<32, false, 0, 2, 2, 32, 32, 4><<<dim3(128,1,4), TPB, 0, stream>>>(
        d0, wTt1, bt1, d1, 32, 32, 32, 64, 64, 64, trs);
    // convT2: d1 -> d2[32,128,128,128]; M=131072/class -> 512 blocks, y=2, z=4
    kConvMM<64, false, 0, 2, 2, 64, 64, 4><<<dim3(512,2,4), TPB, 0, stream>>>(
        d1, wTt2, bt2, d2, 64, 64, 64, 128, 128, 128, trs);

    // convT3 (sigmoid) striped: 8 x 34-row halo stripes, then final convT4
    for (int s8 = 0; s8 < 8; ++s8){
        int r0 = s8 * 32;
        ConvArgs sa{};
        sa.cls[0] = mkTransCls(0, 0, r0/2,     1 - r0);
        sa.cls[1] = mkTransCls(0, 1, r0/2,     1 - r0);
        sa.cls[2] = mkTransCls(1, 0, r0/2 - 1, 2 - r0);
        sa.cls[3] = mkTransCls(1, 1, r0/2 - 1, 2 - r0);
        // M/class = 32*17*128 = 69632 -> 1088 tiles -> 272 blocks
        kConvMM<128, false, 1, 2, 2, 128, 17, 4><<<dim3(272,1,4), TPB, 0, stream>>>(
            d2, wTt3, bt3, st, 128, 128, 128, 64, 34, 256, sa);
        // waves = 32n*32row*64(ow/4) = 65536 -> 16384 blocks
        kConvO4<<<16384, TPB, 0, stream>>>(st, wt4, bt4, out, r0);
    }
}